// Round 9
// baseline (311.044 us; speedup 1.0000x reference)
//
#include <hip/hip_runtime.h>

#define B_SZ 4
#define IN_CH 64
#define OUT_CH 128
#define NHI 163842
#define NLO 40962
#define EPS_GN 1e-5f
#define SLOPE 0.2f

typedef __attribute__((ext_vector_type(8))) short short8;
typedef __attribute__((ext_vector_type(16))) float f32x16;

__device__ inline ushort f2bf(float f) {
    union { float f; unsigned u; } v; v.f = f;
    unsigned r = v.u + 0x7FFF + ((v.u >> 16) & 1);
    return (ushort)(r >> 16);
}
__device__ inline float bf2f(ushort h) {
    union { unsigned u; float f; } v; v.u = ((unsigned)h) << 16;
    return v.f;
}

// ---------------------------------------------------------------------------
// 1) Transpose x: (B,64,NHI) f32 -> xT (B,NHI,64) bf16
// ---------------------------------------------------------------------------
__global__ void k_transpose_x(const float* __restrict__ x, ushort* __restrict__ xT) {
    __shared__ float t[64][65];
    const int b   = blockIdx.y;
    const int n0  = blockIdx.x * 64;
    const int tid = threadIdx.x;
    const int nq  = tid & 15;
    const int c0  = tid >> 4;
    const bool full = (n0 + 64) <= NHI;
    if (full) {
#pragma unroll
        for (int r = 0; r < 4; ++r) {
            int c = c0 + r * 16;
            float4 v = *(const float4*)&x[((long)b * IN_CH + c) * NHI + n0 + nq * 4];
            t[c][nq * 4 + 0] = v.x; t[c][nq * 4 + 1] = v.y;
            t[c][nq * 4 + 2] = v.z; t[c][nq * 4 + 3] = v.w;
        }
    } else {
        for (int r = 0; r < 4; ++r) {
            int c = c0 + r * 16;
            for (int e = 0; e < 4; ++e) {
                int n = n0 + nq * 4 + e;
                t[c][nq * 4 + e] = (n < NHI) ? x[((long)b * IN_CH + c) * NHI + n] : 0.f;
            }
        }
    }
    __syncthreads();
    const int n  = tid >> 2;
    const int cc = (tid & 3) * 16;
    if (n0 + n < NHI) {
        short8 o0, o1;
#pragma unroll
        for (int e = 0; e < 8; ++e) {
            o0[e] = (short)f2bf(t[cc + e][n]);
            o1[e] = (short)f2bf(t[cc + 8 + e][n]);
        }
        ushort* p = &xT[((long)b * NHI + n0 + n) * 64 + cc];
        *(short8*)p = o0;
        *(short8*)(p + 8) = o1;
    }
}

// ---------------------------------------------------------------------------
// 2) Pre-tile weights W (O=128, K) f32 -> Wb bf16:
//    Wb[koct(=k>>3)][o(128)][e(8)]
// ---------------------------------------------------------------------------
__global__ void k_prep_w(const float* __restrict__ W, ushort* __restrict__ Wb, int K) {
    int i = blockIdx.x * 256 + threadIdx.x;
    if (i >= K * 128) return;
    int k = i / 128, o = i % 128;
    int kg = k >> 3, e = k & 7;
    Wb[(((long)kg * 128 + o) * 8) + e] = f2bf(W[(long)o * K + k]);
}

// ---------------------------------------------------------------------------
// 3) Mean pool
// ---------------------------------------------------------------------------
__global__ void k_pool(const ushort* __restrict__ xT, const int* __restrict__ pn,
                       ushort* __restrict__ h1) {
    long t = (long)blockIdx.x * 256 + threadIdx.x;
    const long total = (long)B_SZ * NLO * 8;
    if (t >= total) return;
    int  cq = (int)(t & 7);
    long bn = t >> 3;
    int  n  = (int)(bn % NLO);
    int  b  = (int)(bn / NLO);
    float acc[8] = {};
#pragma unroll
    for (int j = 0; j < 7; ++j) {
        int idx = pn[n * 7 + j];
        short8 v = *(const short8*)&xT[((long)b * NHI + idx) * 64 + cq * 8];
#pragma unroll
        for (int e = 0; e < 8; ++e) acc[e] += bf2f((ushort)v[e]);
    }
    short8 o;
#pragma unroll
    for (int e = 0; e < 8; ++e) o[e] = (short)f2bf(acc[e] * (1.f / 7.f));
    *(short8*)&h1[bn * 64 + cq * 8] = o;
}

// ---------------------------------------------------------------------------
// 4) MFMA one-ring conv: ONE WAVE per block, 32 nodes x 128 outs.
//    No LDS, no __syncthreads, no barriers of any kind in the K-loop.
//    A fragments gathered per-lane directly from global (lane=row of the
//    32x32x16 A operand), register double-buffered across the 7 neighbor
//    steps; B direct from the pre-tiled L2-resident weight image.
//    Every resident wave is an independent, self-paced latency stream.
//    Load order per step: B(j) -> MFMA(j) -> [sched_barrier] A(j+1)
//    [sched_barrier], so vmcnt waits for B never drain the A prefetch.
// ---------------------------------------------------------------------------
template <int CIN>
__global__ __launch_bounds__(64, 2)
void k_conv_mfma(const ushort* __restrict__ src, const int* __restrict__ nbr,
                 const ushort* __restrict__ Wb, const float* __restrict__ bias,
                 ushort* __restrict__ out, float* __restrict__ part) {
    constexpr int KH = CIN / 16;          // MFMAs per neighbor per ntile
    const int b     = blockIdx.y;
    const int n0    = blockIdx.x * 32;
    const int lane  = threadIdx.x;        // 0..63
    const int l31   = lane & 31;
    const int khalf = lane >> 5;

    const int row = min(n0 + l31, NLO - 1);
    int nb[7];
#pragma unroll
    for (int j = 0; j < 7; ++j) nb[j] = nbr[row * 7 + j];

    const long srcb = (long)b * NLO * CIN;
    const int  koff = khalf * 8;          // ushort offset inside a 16-elem kgroup

    f32x16 acc[4] = {};
    short8 abuf[2][KH];

    // prologue: A(0)
    {
        const ushort* p = &src[srcb + (long)nb[0] * CIN + koff];
#pragma unroll
        for (int kh = 0; kh < KH; ++kh) abuf[0][kh] = *(const short8*)(p + kh * 16);
    }

#pragma unroll
    for (int j = 0; j < 7; ++j) {
        // B(j) loads + MFMA cluster (B waits drain only A(j), already needed)
        const ushort* wj = &Wb[(((long)j * 2 * KH + khalf) * 128 + l31) * 8];
#pragma unroll
        for (int kh = 0; kh < KH; ++kh) {
            const ushort* wk = wj + (long)(2 * kh) * 128 * 8;
#pragma unroll
            for (int nt = 0; nt < 4; ++nt) {
                short8 bf = *(const short8*)(wk + nt * 32 * 8);
                acc[nt] = __builtin_amdgcn_mfma_f32_32x32x16_bf16(abuf[j & 1][kh], bf, acc[nt], 0, 0, 0);
            }
        }
        __builtin_amdgcn_sched_barrier(0);
        if (j + 1 < 7) {
            // A(j+1) prefetch: youngest VMEM ops -> fly across next B waits
            const ushort* p = &src[srcb + (long)nb[j + 1] * CIN + koff];
#pragma unroll
            for (int kh = 0; kh < KH; ++kh)
                abuf[(j + 1) & 1][kh] = *(const short8*)(p + kh * 16);
        }
        __builtin_amdgcn_sched_barrier(0);
    }

    // epilogue: bias, bf16 store, per-block GroupNorm partials (g = col>>5 = nt)
    float s[4] = {}, q[4] = {};
#pragma unroll
    for (int nt = 0; nt < 4; ++nt) {
        const float bia = bias[nt * 32 + l31];
#pragma unroll
        for (int r = 0; r < 16; ++r) {
            int crow = (r & 3) + 8 * (r >> 2) + 4 * khalf;
            int orow = n0 + crow;
            float v  = acc[nt][r] + bia;
            if (orow < NLO) {
                out[((long)b * NLO + orow) * 128 + nt * 32 + l31] = f2bf(v);
                s[nt] += v; q[nt] += v * v;
            }
        }
    }
#pragma unroll
    for (int nt = 0; nt < 4; ++nt)
#pragma unroll
        for (int off = 32; off > 0; off >>= 1) {
            s[nt] += __shfl_down(s[nt], off);
            q[nt] += __shfl_down(q[nt], off);
        }
    if (lane == 0) {
        float* pp = &part[((long)b * gridDim.x + blockIdx.x) * 8];
#pragma unroll
        for (int g = 0; g < 4; ++g) { pp[g * 2] = s[g]; pp[g * 2 + 1] = q[g]; }
    }
}

// ---------------------------------------------------------------------------
// 5) Finalize stats -> per (b,c) scale/shift. One block per (b,g).
// ---------------------------------------------------------------------------
__global__ void k_finalize(const float* __restrict__ part, int nblk,
                           const float* __restrict__ w, const float* __restrict__ bb,
                           float* __restrict__ scale, float* __restrict__ shift) {
    const int b = blockIdx.x >> 2, g = blockIdx.x & 3;
    const int tid = threadIdx.x;
    float s = 0.f, ss = 0.f;
    for (int k = tid; k < nblk; k += 256) {
        s  += part[((long)b * nblk + k) * 8 + g * 2 + 0];
        ss += part[((long)b * nblk + k) * 8 + g * 2 + 1];
    }
#pragma unroll
    for (int off = 32; off > 0; off >>= 1) {
        s += __shfl_down(s, off); ss += __shfl_down(ss, off);
    }
    __shared__ float red[8];
    __shared__ float fin[2];
    const int wave = tid >> 6, lane = tid & 63;
    if (lane == 0) { red[wave * 2] = s; red[wave * 2 + 1] = ss; }
    __syncthreads();
    if (tid == 0) {
        float as = red[0] + red[2] + red[4] + red[6];
        float aq = red[1] + red[3] + red[5] + red[7];
        const float cnt = 32.f * NLO;
        float mu  = as / cnt;
        float var = aq / cnt - mu * mu;
        fin[0] = mu; fin[1] = rsqrtf(var + EPS_GN);
    }
    __syncthreads();
    if (tid < 32) {
        int c = g * 32 + tid;
        float sc = fin[1] * w[c];
        scale[b * 128 + c] = sc;
        shift[b * 128 + c] = bb[c] - fin[0] * sc;
    }
}

// ---------------------------------------------------------------------------
// 6) Elementwise gn+leakyrelu: y (B,NLO,128) bf16 -> yp bf16
// ---------------------------------------------------------------------------
__global__ void k_gnapply(const ushort* __restrict__ y, const float* __restrict__ sc,
                          const float* __restrict__ sh, ushort* __restrict__ yp) {
    long t = (long)blockIdx.x * 256 + threadIdx.x;
    const long total = (long)B_SZ * NLO * 16;
    if (t >= total) return;
    int  c8 = (int)(t & 15);
    long bn = t >> 4;
    int  b  = (int)(bn / NLO);
    short8 v = *(const short8*)&y[bn * 128 + c8 * 8];
    short8 o;
#pragma unroll
    for (int e = 0; e < 8; ++e) {
        int c = c8 * 8 + e;
        float f = bf2f((ushort)v[e]) * sc[b * 128 + c] + sh[b * 128 + c];
        f = fmaxf(f, SLOPE * f);
        o[e] = (short)f2bf(f);
    }
    *(short8*)&yp[bn * 128 + c8 * 8] = o;
}

// ---------------------------------------------------------------------------
// 7) Output: gn2 + leakyrelu + transpose (B,N,128) bf16 -> (B,128,N) f32
// ---------------------------------------------------------------------------
__global__ void k_output(const ushort* __restrict__ y2, const float* __restrict__ scale,
                         const float* __restrict__ shift, float* __restrict__ out) {
    __shared__ float t[32][129];
    const int b   = blockIdx.y;
    const int n0  = blockIdx.x * 32;
    const int tid = threadIdx.x;
    const float* scb = &scale[b * 128];
    const float* shb = &shift[b * 128];
    const int c8 = (tid & 15) * 8;
#pragma unroll
    for (int r = 0; r < 2; ++r) {
        int nn = (tid >> 4) + r * 16;
        int n  = n0 + nn;
        if (n < NLO) {
            short8 v = *(const short8*)&y2[((long)b * NLO + n) * 128 + c8];
#pragma unroll
            for (int e = 0; e < 8; ++e) {
                int c = c8 + e;
                float f = bf2f((ushort)v[e]) * scb[c] + shb[c];
                t[nn][c] = fmaxf(f, SLOPE * f);
            }
        } else {
#pragma unroll
            for (int e = 0; e < 8; ++e) t[nn][c8 + e] = 0.f;
        }
    }
    __syncthreads();
    const int n4 = (tid & 7) * 4;
    const bool full = (n0 + 32) <= NLO;
#pragma unroll
    for (int r = 0; r < 4; ++r) {
        int c = (tid >> 3) + r * 32;
        long o = ((long)b * 128 + c) * NLO + n0 + n4;
        if (full) {
            float2 v0 = make_float2(t[n4][c], t[n4 + 1][c]);
            float2 v1 = make_float2(t[n4 + 2][c], t[n4 + 3][c]);
            *(float2*)&out[o]     = v0;
            *(float2*)&out[o + 2] = v1;
        } else {
            for (int e = 0; e < 4; ++e)
                if (n0 + n4 + e < NLO) out[o + e] = t[n4 + e][c];
        }
    }
}

// ---------------------------------------------------------------------------
// Launch
// ---------------------------------------------------------------------------
extern "C" void kernel_launch(void* const* d_in, const int* in_sizes, int n_in,
                              void* d_out, int out_size, void* d_ws, size_t ws_size,
                              hipStream_t stream) {
    const float* x   = (const float*)d_in[0];
    const int*   pn  = (const int*)d_in[1];
    const int*   cn  = (const int*)d_in[2];
    const float* W1  = (const float*)d_in[3];
    const float* b1  = (const float*)d_in[4];
    const float* g1w = (const float*)d_in[5];
    const float* g1b = (const float*)d_in[6];
    const float* W2  = (const float*)d_in[7];
    const float* b2  = (const float*)d_in[8];
    const float* g2w = (const float*)d_in[9];
    const float* g2b = (const float*)d_in[10];
    float* out = (float*)d_out;
    char*  base = (char*)d_ws;

    ushort* xT  = (ushort*)(base + 0);           // 83,887,104 B
    ushort* y1  = (ushort*)(base + 0);           // reuse (xT dead after pool)
    ushort* y1p = (ushort*)(base + 44000000);
    ushort* h1  = (ushort*)(base + 88000000);    // dead after conv1
    ushort* y2  = (ushort*)(base + 110000000);   // written only by conv2
    ushort* wb1 = (ushort*)(base + 152000000);
    ushort* wb2 = (ushort*)(base + 152200000);
    // p1 lives in the (not-yet-written) y2 region: consumed by finalize1
    // BEFORE conv2 writes y2.  p2 lives in the dead h1 region.
    float*  p1  = (float*)(base + 110000000);    // 4*1281*8*4 = 164 KB
    float*  p2  = (float*)(base + 88000000);
    float*  sc1 = (float*)(base + 152700000);
    float*  sh1 = sc1 + 512;
    float*  sc2 = (float*)(base + 152710000);
    float*  sh2 = sc2 + 512;

    const int NBLK = (NLO + 31) / 32;  // 1281 one-wave conv blocks per batch

    k_transpose_x<<<dim3((NHI + 63) / 64, B_SZ), 256, 0, stream>>>(x, xT);
    k_prep_w<<<(448 * 128 + 255) / 256, 256, 0, stream>>>(W1, wb1, 448);
    k_prep_w<<<(896 * 128 + 255) / 256, 256, 0, stream>>>(W2, wb2, 896);
    k_pool<<<(int)(((long)B_SZ * NLO * 8 + 255) / 256), 256, 0, stream>>>(xT, pn, h1);
    k_conv_mfma<64><<<dim3(NBLK, B_SZ), 64, 0, stream>>>(h1, cn, wb1, b1, y1, p1);
    k_finalize<<<16, 256, 0, stream>>>(p1, NBLK, g1w, g1b, sc1, sh1);
    k_gnapply<<<(int)(((long)B_SZ * NLO * 16 + 255) / 256), 256, 0, stream>>>(y1, sc1, sh1, y1p);
    k_conv_mfma<128><<<dim3(NBLK, B_SZ), 64, 0, stream>>>(y1p, cn, wb2, b2, y2, p2);
    k_finalize<<<16, 256, 0, stream>>>(p2, NBLK, g2w, g2b, sc2, sh2);
    k_output<<<dim3((NLO + 31) / 32, B_SZ), 256, 0, stream>>>(y2, sc2, sh2, out);
}

// Round 10
// 264.088 us; speedup vs baseline: 1.1778x; 1.1778x over previous
//
#include <hip/hip_runtime.h>

#define B_SZ 4
#define IN_CH 64
#define OUT_CH 128
#define NHI 163842
#define NLO 40962
#define EPS_GN 1e-5f
#define SLOPE 0.2f

typedef __attribute__((ext_vector_type(8))) short short8;
typedef __attribute__((ext_vector_type(8))) float float8;
typedef __attribute__((ext_vector_type(16))) float f32x16;

__device__ inline ushort f2bf(float f) {
    union { float f; unsigned u; } v; v.f = f;
    unsigned r = v.u + 0x7FFF + ((v.u >> 16) & 1);
    return (ushort)(r >> 16);
}
__device__ inline float bf2f(ushort h) {
    union { unsigned u; float f; } v; v.u = ((unsigned)h) << 16;
    return v.f;
}

// async global->LDS, 16B per lane; LDS dest = uniform base + lane*16
__device__ inline void glds16(const ushort* g, ushort* l) {
    typedef __attribute__((address_space(1))) const void gv;
    typedef __attribute__((address_space(3))) void lv;
    __builtin_amdgcn_global_load_lds((gv*)g, (lv*)l, 16, 0, 0);
}

// ---------------------------------------------------------------------------
// 1) Transpose x: (B,64,NHI) f32 -> xT (B,NHI,64) bf16
// ---------------------------------------------------------------------------
__global__ void k_transpose_x(const float* __restrict__ x, ushort* __restrict__ xT) {
    __shared__ float t[64][65];
    const int b   = blockIdx.y;
    const int n0  = blockIdx.x * 64;
    const int tid = threadIdx.x;
    const int nq  = tid & 15;
    const int c0  = tid >> 4;
    const bool full = (n0 + 64) <= NHI;
    if (full) {
#pragma unroll
        for (int r = 0; r < 4; ++r) {
            int c = c0 + r * 16;
            float4 v = *(const float4*)&x[((long)b * IN_CH + c) * NHI + n0 + nq * 4];
            t[c][nq * 4 + 0] = v.x; t[c][nq * 4 + 1] = v.y;
            t[c][nq * 4 + 2] = v.z; t[c][nq * 4 + 3] = v.w;
        }
    } else {
        for (int r = 0; r < 4; ++r) {
            int c = c0 + r * 16;
            for (int e = 0; e < 4; ++e) {
                int n = n0 + nq * 4 + e;
                t[c][nq * 4 + e] = (n < NHI) ? x[((long)b * IN_CH + c) * NHI + n] : 0.f;
            }
        }
    }
    __syncthreads();
    const int n  = tid >> 2;
    const int cc = (tid & 3) * 16;
    if (n0 + n < NHI) {
        short8 o0, o1;
#pragma unroll
        for (int e = 0; e < 8; ++e) {
            o0[e] = (short)f2bf(t[cc + e][n]);
            o1[e] = (short)f2bf(t[cc + 8 + e][n]);
        }
        ushort* p = &xT[((long)b * NHI + n0 + n) * 64 + cc];
        *(short8*)p = o0;
        *(short8*)(p + 8) = o1;
    }
}

// ---------------------------------------------------------------------------
// 2) Pre-tile weights W (O=128, K) f32 -> Wb bf16 in the conv LDS image:
//    Wb[step][kg(8)][o(128)][e(8)]  where k = step*64 + kg*8 + e
// ---------------------------------------------------------------------------
__global__ void k_prep_w(const float* __restrict__ W, ushort* __restrict__ Wb, int K) {
    int i = blockIdx.x * 256 + threadIdx.x;
    if (i >= K * 128) return;
    int k = i / 128, o = i % 128;
    int step = k >> 6, kk = k & 63, kg = kk >> 3, e = kk & 7;
    Wb[(((long)(step * 8 + kg) * 128 + o) * 8) + e] = f2bf(W[(long)o * K + k]);
}

// ---------------------------------------------------------------------------
// 3) Mean pool
// ---------------------------------------------------------------------------
__global__ void k_pool(const ushort* __restrict__ xT, const int* __restrict__ pn,
                       ushort* __restrict__ h1) {
    long t = (long)blockIdx.x * 256 + threadIdx.x;
    const long total = (long)B_SZ * NLO * 8;
    if (t >= total) return;
    int  cq = (int)(t & 7);
    long bn = t >> 3;
    int  n  = (int)(bn % NLO);
    int  b  = (int)(bn / NLO);
    float acc[8] = {};
#pragma unroll
    for (int j = 0; j < 7; ++j) {
        int idx = pn[n * 7 + j];
        short8 v = *(const short8*)&xT[((long)b * NHI + idx) * 64 + cq * 8];
#pragma unroll
        for (int e = 0; e < 8; ++e) acc[e] += bf2f((ushort)v[e]);
    }
    short8 o;
#pragma unroll
    for (int e = 0; e < 8; ++e) o[e] = (short)f2bf(acc[e] * (1.f / 7.f));
    *(short8*)&h1[bn * 64 + cq * 8] = o;
}

// Swizzled A-image index: (kg, nn[0..127]) -> ushort offset.  XOR of kg into
// nn bits 1..3 makes staging WRITES (4 lanes, same nn, kg 0..3 / 4..7) and
// fragment READS (32 consecutive nn, fixed kg) both conflict-free.  [R7: 0]
__device__ inline int aidx(int kg, int nn) {
    return (kg * 128 + (nn ^ ((kg & 7) << 1))) * 8;
}

// ---------------------------------------------------------------------------
// 4) MFMA one-ring conv (R4 structure + fixes). Block 128 nodes x 128 outs,
//    512 threads (8 waves, 4x2), wave tile 32x64, BK=64, double-buffered.
//    - A: coalesced gather -> regs -> swizzled LDS (conflict-free writes).
//      Depth-2 pipeline: A(s+2) loads issued at step s, so the ds_write of
//      A(s+1) waits on loads a FULL step old (~500+ cyc of coverage).
//    - B: global_load_lds DMA into linear LDS image (wave-shared: ~4x less
//      L2 weight traffic than B-direct; no VGPR round-trip).
//    - FUSE: gn1+leakyrelu applied at A-staging time (kills k_gnapply pass).
//    One barrier per K-step.
// ---------------------------------------------------------------------------
template <int CIN, bool FUSE>
__global__ __launch_bounds__(512, 4)
void k_conv_mfma(const ushort* __restrict__ src, const int* __restrict__ nbr,
                 const ushort* __restrict__ Wb, const float* __restrict__ bias,
                 const float* __restrict__ gsc, const float* __restrict__ gsh,
                 ushort* __restrict__ out, float* __restrict__ part) {
    constexpr int NSTEP = 7 * CIN / 64;
    __shared__ ushort Asm[2][8192];     // 16KB per buffer, swizzled image
    __shared__ ushort Bsm[2][8192];     // 16KB per buffer, linear (glds dest)
    __shared__ float  red[8][2][2];

    const int b     = blockIdx.y;
    const int n0    = blockIdx.x * 128;
    const int tid   = threadIdx.x;
    const int lane  = tid & 63;
    const int wave  = tid >> 6;          // 0..7
    const int wr    = wave >> 1, wc = wave & 1;
    const int l31   = lane & 31;
    const int khalf = lane >> 5;

    // A staging: 4 threads per node row; each thread stages kg {s_kq, s_kq+4}
    const int s_nn = tid >> 2;           // 0..127
    const int s_kq = tid & 3;
    const int nrow = min(n0 + s_nn, NLO - 1);
    int nb[7];
#pragma unroll
    for (int j = 0; j < 7; ++j) nb[j] = nbr[nrow * 7 + j];

    const long srcb = (long)b * NLO * CIN;
    f32x16 acc0 = {}, acc1 = {};
    short8 a[2][2];                      // [step parity][chunk]

    // helpers -------------------------------------------------------------
    auto loadA = [&](int t, short8* dst) {
        const int j  = (CIN == 64) ? t : (t >> 1);
        const int cb = (CIN == 64) ? 0 : ((t & 1) * 64);
        const ushort* p = &src[srcb + (long)nb[j] * CIN + cb + s_kq * 8];
        dst[0] = *(const short8*)p;
        dst[1] = *(const short8*)(p + 32);
    };
    auto writeA = [&](int buf, int t, short8* v) {
        short8 w0 = v[0], w1 = v[1];
        if (FUSE) {
            const int cb = (t & 1) * 64;   // CIN==128 only when FUSE
            float8 sc0 = *(const float8*)&gsc[b * 128 + cb + s_kq * 8];
            float8 sh0 = *(const float8*)&gsh[b * 128 + cb + s_kq * 8];
            float8 sc1 = *(const float8*)&gsc[b * 128 + cb + s_kq * 8 + 32];
            float8 sh1 = *(const float8*)&gsh[b * 128 + cb + s_kq * 8 + 32];
#pragma unroll
            for (int e = 0; e < 8; ++e) {
                float f0 = bf2f((ushort)w0[e]) * sc0[e] + sh0[e];
                float f1 = bf2f((ushort)w1[e]) * sc1[e] + sh1[e];
                w0[e] = (short)f2bf(fmaxf(f0, SLOPE * f0));
                w1[e] = (short)f2bf(fmaxf(f1, SLOPE * f1));
            }
        }
        *(short8*)&Asm[buf][aidx(s_kq,     s_nn)] = w0;
        *(short8*)&Asm[buf][aidx(s_kq + 4, s_nn)] = w1;
    };
    auto gldsB = [&](int t, int buf) {
        glds16(&Wb[(long)t * 8192 + tid * 8],        &Bsm[buf][tid * 8]);
        glds16(&Wb[(long)t * 8192 + tid * 8 + 4096], &Bsm[buf][tid * 8 + 4096]);
    };

    // prologue: B(0) DMA; A(0), A(1) loads; A(0) -> LDS
    gldsB(0, 0);
    loadA(0, a[0]);
    if (NSTEP > 1) loadA(1, a[1]);
    writeA(0, 0, a[0]);
    __syncthreads();   // drains B(0) DMA + A(0) writes

#pragma unroll
    for (int s = 0; s < NSTEP; ++s) {
        const int cur = s & 1, nxt = cur ^ 1;
        if (s + 1 < NSTEP) {
            gldsB(s + 1, nxt);               // B DMA in flight across MFMAs
            writeA(nxt, s + 1, a[(s + 1) & 1]); // waits loads issued step s-1
        }
        if (s + 2 < NSTEP) loadA(s + 2, a[s & 1]);  // depth-2 A prefetch
#pragma unroll
        for (int kh = 0; kh < 4; ++kh) {
            const int kg = 2 * kh + khalf;
            short8 A0 = *(const short8*)&Asm[cur][aidx(kg, wr * 32 + l31)];
            short8 B0 = *(const short8*)&Bsm[cur][(kg * 128 + wc * 64 + l31) * 8];
            short8 B1 = *(const short8*)&Bsm[cur][(kg * 128 + wc * 64 + 32 + l31) * 8];
            acc0 = __builtin_amdgcn_mfma_f32_32x32x16_bf16(A0, B0, acc0, 0, 0, 0);
            acc1 = __builtin_amdgcn_mfma_f32_32x32x16_bf16(A0, B1, acc1, 0, 0, 0);
        }
        __syncthreads();   // drains B-DMA(nxt) + A writes; orders buffers
    }

    // epilogue: bias, bf16 store, per-block GroupNorm partials
    const float bias0 = bias[wc * 64 + l31];
    const float bias1 = bias[wc * 64 + 32 + l31];
    float s0 = 0.f, q0 = 0.f, s1 = 0.f, q1 = 0.f;
#pragma unroll
    for (int r = 0; r < 16; ++r) {
        int rrow = (r & 3) + 8 * (r >> 2) + 4 * khalf + wr * 32;
        int n = n0 + rrow;
        float v0 = acc0[r] + bias0;
        float v1 = acc1[r] + bias1;
        if (n < NLO) {
            long o = ((long)b * NLO + n) * 128 + wc * 64 + l31;
            out[o]      = f2bf(v0);
            out[o + 32] = f2bf(v1);
            s0 += v0; q0 += v0 * v0;
            s1 += v1; q1 += v1 * v1;
        }
    }
#pragma unroll
    for (int off = 32; off > 0; off >>= 1) {
        s0 += __shfl_down(s0, off); q0 += __shfl_down(q0, off);
        s1 += __shfl_down(s1, off); q1 += __shfl_down(q1, off);
    }
    if (lane == 0) { red[wave][0][0] = s0; red[wave][0][1] = q0;
                     red[wave][1][0] = s1; red[wave][1][1] = q1; }
    __syncthreads();
    if (tid < 8) {
        int g = tid >> 1, isq = tid & 1;      // g = wc*2 + n32
        int gwc = g >> 1, gn = g & 1;
        float v = 0.f;
#pragma unroll
        for (int w = 0; w < 4; ++w) v += red[w * 2 + gwc][gn][isq];
        part[(((long)b * gridDim.x + blockIdx.x) * 4 + g) * 2 + isq] = v;
    }
}

// ---------------------------------------------------------------------------
// 5) Finalize stats -> per (b,c) scale/shift. One block per (b,g).
// ---------------------------------------------------------------------------
__global__ void k_finalize(const float* __restrict__ part, int nblk,
                           const float* __restrict__ w, const float* __restrict__ bb,
                           float* __restrict__ scale, float* __restrict__ shift) {
    const int b = blockIdx.x >> 2, g = blockIdx.x & 3;
    const int tid = threadIdx.x;
    float s = 0.f, ss = 0.f;
    for (int k = tid; k < nblk; k += 256) {
        s  += part[(((long)b * nblk + k) * 4 + g) * 2 + 0];
        ss += part[(((long)b * nblk + k) * 4 + g) * 2 + 1];
    }
#pragma unroll
    for (int off = 32; off > 0; off >>= 1) {
        s += __shfl_down(s, off); ss += __shfl_down(ss, off);
    }
    __shared__ float red[8];
    __shared__ float fin[2];
    const int wave = tid >> 6, lane = tid & 63;
    if (lane == 0) { red[wave * 2] = s; red[wave * 2 + 1] = ss; }
    __syncthreads();
    if (tid == 0) {
        float as = red[0] + red[2] + red[4] + red[6];
        float aq = red[1] + red[3] + red[5] + red[7];
        const float cnt = 32.f * NLO;
        float mu  = as / cnt;
        float var = aq / cnt - mu * mu;
        fin[0] = mu; fin[1] = rsqrtf(var + EPS_GN);
    }
    __syncthreads();
    if (tid < 32) {
        int c = g * 32 + tid;
        float sc = fin[1] * w[c];
        scale[b * 128 + c] = sc;
        shift[b * 128 + c] = bb[c] - fin[0] * sc;
    }
}

// ---------------------------------------------------------------------------
// 6) Output: gn2 + leakyrelu + transpose (B,N,128) bf16 -> (B,128,N) f32
// ---------------------------------------------------------------------------
__global__ void k_output(const ushort* __restrict__ y2, const float* __restrict__ scale,
                         const float* __restrict__ shift, float* __restrict__ out) {
    __shared__ float t[32][129];
    const int b   = blockIdx.y;
    const int n0  = blockIdx.x * 32;
    const int tid = threadIdx.x;
    const float* scb = &scale[b * 128];
    const float* shb = &shift[b * 128];
    const int c8 = (tid & 15) * 8;
#pragma unroll
    for (int r = 0; r < 2; ++r) {
        int nn = (tid >> 4) + r * 16;
        int n  = n0 + nn;
        if (n < NLO) {
            short8 v = *(const short8*)&y2[((long)b * NLO + n) * 128 + c8];
#pragma unroll
            for (int e = 0; e < 8; ++e) {
                int c = c8 + e;
                float f = bf2f((ushort)v[e]) * scb[c] + shb[c];
                t[nn][c] = fmaxf(f, SLOPE * f);
            }
        } else {
#pragma unroll
            for (int e = 0; e < 8; ++e) t[nn][c8 + e] = 0.f;
        }
    }
    __syncthreads();
    const int n4 = (tid & 7) * 4;
    const bool full = (n0 + 32) <= NLO;
#pragma unroll
    for (int r = 0; r < 4; ++r) {
        int c = (tid >> 3) + r * 32;
        long o = ((long)b * 128 + c) * NLO + n0 + n4;
        if (full) {
            float2 v0 = make_float2(t[n4][c], t[n4 + 1][c]);
            float2 v1 = make_float2(t[n4 + 2][c], t[n4 + 3][c]);
            *(float2*)&out[o]     = v0;
            *(float2*)&out[o + 2] = v1;
        } else {
            for (int e = 0; e < 4; ++e)
                if (n0 + n4 + e < NLO) out[o + e] = t[n4 + e][c];
        }
    }
}

// ---------------------------------------------------------------------------
// Launch
// ---------------------------------------------------------------------------
extern "C" void kernel_launch(void* const* d_in, const int* in_sizes, int n_in,
                              void* d_out, int out_size, void* d_ws, size_t ws_size,
                              hipStream_t stream) {
    const float* x   = (const float*)d_in[0];
    const int*   pn  = (const int*)d_in[1];
    const int*   cn  = (const int*)d_in[2];
    const float* W1  = (const float*)d_in[3];
    const float* b1  = (const float*)d_in[4];
    const float* g1w = (const float*)d_in[5];
    const float* g1b = (const float*)d_in[6];
    const float* W2  = (const float*)d_in[7];
    const float* b2  = (const float*)d_in[8];
    const float* g2w = (const float*)d_in[9];
    const float* g2b = (const float*)d_in[10];
    float* out = (float*)d_out;
    char*  base = (char*)d_ws;

    ushort* xT  = (ushort*)(base + 0);           // 83,887,104 B
    ushort* y1  = (ushort*)(base + 0);           // reuse (xT dead after pool)
    ushort* h1  = (ushort*)(base + 88000000);    // dead after conv1
    ushort* y2  = (ushort*)(base + 110000000);   // 41,945,088 B (ends <152M)
    ushort* wb1 = (ushort*)(base + 152000000);   // 114,688 B
    ushort* wb2 = (ushort*)(base + 152200000);   // 229,376 B
    // p1 in (not-yet-written) y2 region, consumed by finalize1 before conv2;
    // p2 in dead h1 region.
    float*  p1  = (float*)(base + 110000000);
    float*  p2  = (float*)(base + 88000000);
    float*  sc1 = (float*)(base + 152700000);    // 32B-aligned
    float*  sh1 = sc1 + 512;
    float*  sc2 = (float*)(base + 152720000);    // 32B-aligned
    float*  sh2 = sc2 + 512;

    const int NBLK = (NLO + 127) / 128;  // 321 conv blocks per batch

    k_transpose_x<<<dim3((NHI + 63) / 64, B_SZ), 256, 0, stream>>>(x, xT);
    k_prep_w<<<(448 * 128 + 255) / 256, 256, 0, stream>>>(W1, wb1, 448);
    k_prep_w<<<(896 * 128 + 255) / 256, 256, 0, stream>>>(W2, wb2, 896);
    k_pool<<<(int)(((long)B_SZ * NLO * 8 + 255) / 256), 256, 0, stream>>>(xT, pn, h1);
    k_conv_mfma<64, false><<<dim3(NBLK, B_SZ), 512, 0, stream>>>(
        h1, cn, wb1, b1, nullptr, nullptr, y1, p1);
    k_finalize<<<16, 256, 0, stream>>>(p1, NBLK, g1w, g1b, sc1, sh1);
    // conv2 gathers raw y1 and applies gn1+leakyrelu during A-staging (fused)
    k_conv_mfma<128, true><<<dim3(NBLK, B_SZ), 512, 0, stream>>>(
        y1, cn, wb2, b2, sc1, sh1, y2, p2);
    k_finalize<<<16, 256, 0, stream>>>(p2, NBLK, g2w, g2b, sc2, sh2);
    k_output<<<dim3((NLO + 31) / 32, B_SZ), 256, 0, stream>>>(y2, sc2, sh2, out);
}

// Round 11
// 244.371 us; speedup vs baseline: 1.2728x; 1.0807x over previous
//
#include <hip/hip_runtime.h>

#define B_SZ 4
#define IN_CH 64
#define OUT_CH 128
#define NHI 163842
#define NLO 40962
#define EPS_GN 1e-5f
#define SLOPE 0.2f

typedef __attribute__((ext_vector_type(8))) short short8;
typedef __attribute__((ext_vector_type(16))) float f32x16;

__device__ inline ushort f2bf(float f) {
    union { float f; unsigned u; } v; v.f = f;
    unsigned r = v.u + 0x7FFF + ((v.u >> 16) & 1);
    return (ushort)(r >> 16);
}
__device__ inline float bf2f(ushort h) {
    union { unsigned u; float f; } v; v.u = ((unsigned)h) << 16;
    return v.f;
}

// ---------------------------------------------------------------------------
// 1) Transpose x: (B,64,NHI) f32 -> xT (B,NHI,64) bf16
// ---------------------------------------------------------------------------
__global__ void k_transpose_x(const float* __restrict__ x, ushort* __restrict__ xT) {
    __shared__ float t[64][65];
    const int b   = blockIdx.y;
    const int n0  = blockIdx.x * 64;
    const int tid = threadIdx.x;
    const int nq  = tid & 15;
    const int c0  = tid >> 4;
    const bool full = (n0 + 64) <= NHI;
    if (full) {
#pragma unroll
        for (int r = 0; r < 4; ++r) {
            int c = c0 + r * 16;
            float4 v = *(const float4*)&x[((long)b * IN_CH + c) * NHI + n0 + nq * 4];
            t[c][nq * 4 + 0] = v.x; t[c][nq * 4 + 1] = v.y;
            t[c][nq * 4 + 2] = v.z; t[c][nq * 4 + 3] = v.w;
        }
    } else {
        for (int r = 0; r < 4; ++r) {
            int c = c0 + r * 16;
            for (int e = 0; e < 4; ++e) {
                int n = n0 + nq * 4 + e;
                t[c][nq * 4 + e] = (n < NHI) ? x[((long)b * IN_CH + c) * NHI + n] : 0.f;
            }
        }
    }
    __syncthreads();
    const int n  = tid >> 2;
    const int cc = (tid & 3) * 16;
    if (n0 + n < NHI) {
        short8 o0, o1;
#pragma unroll
        for (int e = 0; e < 8; ++e) {
            o0[e] = (short)f2bf(t[cc + e][n]);
            o1[e] = (short)f2bf(t[cc + 8 + e][n]);
        }
        ushort* p = &xT[((long)b * NHI + n0 + n) * 64 + cc];
        *(short8*)p = o0;
        *(short8*)(p + 8) = o1;
    }
}

// ---------------------------------------------------------------------------
// 2) Pre-tile weights W (O=128, K) f32 -> Wb bf16 in the conv LDS image:
//    Wb[step][kg(8)][o(128)][e(8)]  where k = step*64 + kg*8 + e
// ---------------------------------------------------------------------------
__global__ void k_prep_w(const float* __restrict__ W, ushort* __restrict__ Wb, int K) {
    int i = blockIdx.x * 256 + threadIdx.x;
    if (i >= K * 128) return;
    int k = i / 128, o = i % 128;
    int step = k >> 6, kk = k & 63, kg = kk >> 3, e = kk & 7;
    Wb[(((long)(step * 8 + kg) * 128 + o) * 8) + e] = f2bf(W[(long)o * K + k]);
}

// ---------------------------------------------------------------------------
// 3) Mean pool
// ---------------------------------------------------------------------------
__global__ void k_pool(const ushort* __restrict__ xT, const int* __restrict__ pn,
                       ushort* __restrict__ h1) {
    long t = (long)blockIdx.x * 256 + threadIdx.x;
    const long total = (long)B_SZ * NLO * 8;
    if (t >= total) return;
    int  cq = (int)(t & 7);
    long bn = t >> 3;
    int  n  = (int)(bn % NLO);
    int  b  = (int)(bn / NLO);
    float acc[8] = {};
#pragma unroll
    for (int j = 0; j < 7; ++j) {
        int idx = pn[n * 7 + j];
        short8 v = *(const short8*)&xT[((long)b * NHI + idx) * 64 + cq * 8];
#pragma unroll
        for (int e = 0; e < 8; ++e) acc[e] += bf2f((ushort)v[e]);
    }
    short8 o;
#pragma unroll
    for (int e = 0; e < 8; ++e) o[e] = (short)f2bf(acc[e] * (1.f / 7.f));
    *(short8*)&h1[bn * 64 + cq * 8] = o;
}

// Swizzled A-image index: (kg, nn[0..127]) -> ushort offset.
// Writes: an 8-lane quad (s_nn fixed pair, s_kq 0..3) hits banks
// {0,8,16,24}+{4,12,20,28} -> conflict-free (was 4-way, 6.9M conflicts).
// Reads: XOR by const <16 permutes 32 distinct rows in-span -> conflict-free.
__device__ inline int aidx(int kg, int nn) {
    return (kg * 128 + (nn ^ (kg << 1))) * 8;
}

// ---------------------------------------------------------------------------
// 4) MFMA one-ring conv — EXACT R4 structure (best measured: conv2 < 93us)
//    + A-image XOR swizzle (fixes R4's measured 4-way staging-write conflict).
//    Block 128 nodes x 128 outs, 512 threads (8 waves, 4x2), wave 32x64,
//    BK=64, double-buffered LDS, ONE barrier per step:
//      write(cur) -> barrier -> prefetch-loads(next) -> MFMA(cur)
// ---------------------------------------------------------------------------
template <int CIN>
__global__ __launch_bounds__(512, 4)
void k_conv_mfma(const ushort* __restrict__ src, const int* __restrict__ nbr,
                 const ushort* __restrict__ Wb, const float* __restrict__ bias,
                 ushort* __restrict__ out, float* __restrict__ part) {
    constexpr int K = 7 * CIN;
    constexpr int NSTEP = K / 64;
    __shared__ ushort Asm[2][8192];   // 16KB per buf, swizzled [kg][nn][e]
    __shared__ ushort Bsm[2][8192];   // 16KB per buf, linear   [kg][o][e]
    __shared__ float  red[8][4];

    const int b    = blockIdx.y;
    const int n0   = blockIdx.x * 128;
    const int tid  = threadIdx.x;
    const int lane = tid & 63;
    const int wave = tid >> 6;               // 0..7
    const int wr   = wave >> 1, wc = wave & 1;

    // A staging: 4 threads per node, 2 chunks of 8 channels (kg s_kq, s_kq+4)
    const int s_nn = tid >> 2;               // 0..127
    const int s_kq = tid & 3;
    int nrow = n0 + s_nn; if (nrow >= NLO) nrow = NLO - 1;
    const int* nbr_row = &nbr[nrow * 7];

    f32x16 acc0 = {}, acc1 = {};
    const long srcb = (long)b * NLO * CIN;

    const int arow  = wr * 32 + (lane & 31);
    const int bcol0 = wc * 64 + (lane & 31);
    const int khalf = lane >> 5;

    short8 a0, a1, w0, w1;
    // prologue load, step 0
    {
        const ushort* sp = &src[srcb + (long)nbr_row[0] * CIN + s_kq * 8];
        a0 = *(const short8*)sp;
        a1 = *(const short8*)(sp + 32);
        const ushort* wp = &Wb[tid * 16];
        w0 = *(const short8*)wp;
        w1 = *(const short8*)(wp + 8);
    }

    for (int step = 0; step < NSTEP; ++step) {
        const int cur = step & 1;
        *(short8*)&Asm[cur][aidx(s_kq,     s_nn)] = a0;
        *(short8*)&Asm[cur][aidx(s_kq + 4, s_nn)] = a1;
        *(short8*)&Bsm[cur][tid * 16]     = w0;
        *(short8*)&Bsm[cur][tid * 16 + 8] = w1;
        __syncthreads();
        if (step + 1 < NSTEP) {
            int s = step + 1, j, cbase;
            if (CIN == 64) { j = s; cbase = 0; }
            else           { j = s >> 1; cbase = (s & 1) * 64; }
            const ushort* sp = &src[srcb + (long)nbr_row[j] * CIN + cbase + s_kq * 8];
            a0 = *(const short8*)sp;
            a1 = *(const short8*)(sp + 32);
            const ushort* wp = &Wb[(long)s * 8192 + tid * 16];
            w0 = *(const short8*)wp;
            w1 = *(const short8*)(wp + 8);
        }
#pragma unroll
        for (int kh = 0; kh < 4; ++kh) {
            int kg = 2 * kh + khalf;
            short8 af  = *(const short8*)&Asm[cur][aidx(kg, arow)];
            short8 bf0 = *(const short8*)&Bsm[cur][(kg * 128 + bcol0) * 8];
            short8 bf1 = *(const short8*)&Bsm[cur][(kg * 128 + bcol0 + 32) * 8];
            acc0 = __builtin_amdgcn_mfma_f32_32x32x16_bf16(af, bf0, acc0, 0, 0, 0);
            acc1 = __builtin_amdgcn_mfma_f32_32x32x16_bf16(af, bf1, acc1, 0, 0, 0);
        }
        // single barrier per step: next iter writes the other buffer.
    }

    // epilogue: bias, bf16 store, per-block GroupNorm partials
    const float bias0 = bias[wc * 64 + (lane & 31)];
    const float bias1 = bias[wc * 64 + 32 + (lane & 31)];
    float s0 = 0.f, q0 = 0.f, s1 = 0.f, q1 = 0.f;
#pragma unroll
    for (int r = 0; r < 16; ++r) {
        int rrow = (r & 3) + 8 * (r >> 2) + 4 * khalf + wr * 32;
        int n = n0 + rrow;
        float v0 = acc0[r] + bias0;
        float v1 = acc1[r] + bias1;
        if (n < NLO) {
            long o = ((long)b * NLO + n) * 128 + wc * 64 + (lane & 31);
            out[o]      = f2bf(v0);
            out[o + 32] = f2bf(v1);
            s0 += v0; q0 += v0 * v0;
            s1 += v1; q1 += v1 * v1;
        }
    }
#pragma unroll
    for (int off = 32; off > 0; off >>= 1) {
        s0 += __shfl_down(s0, off); q0 += __shfl_down(q0, off);
        s1 += __shfl_down(s1, off); q1 += __shfl_down(q1, off);
    }
    if (lane == 0) { red[wave][0] = s0; red[wave][1] = q0; red[wave][2] = s1; red[wave][3] = q1; }
    __syncthreads();
    if (tid < 8) {
        int g = tid >> 1, isq = tid & 1;
        int wcg = g >> 1, ct = g & 1;
        float v = 0.f;
#pragma unroll
        for (int w = 0; w < 4; ++w) v += red[w * 2 + wcg][ct * 2 + isq];
        part[(((long)b * gridDim.x + blockIdx.x) * 4 + g) * 2 + isq] = v;
    }
}

// ---------------------------------------------------------------------------
// 5) Finalize stats -> per (b,c) scale/shift. One block per (b,g).
// ---------------------------------------------------------------------------
__global__ void k_finalize(const float* __restrict__ part, int nblk,
                           const float* __restrict__ w, const float* __restrict__ bb,
                           float* __restrict__ scale, float* __restrict__ shift) {
    const int b = blockIdx.x >> 2, g = blockIdx.x & 3;
    const int tid = threadIdx.x;
    float s = 0.f, ss = 0.f;
    for (int k = tid; k < nblk; k += 256) {
        s  += part[(((long)b * nblk + k) * 4 + g) * 2 + 0];
        ss += part[(((long)b * nblk + k) * 4 + g) * 2 + 1];
    }
#pragma unroll
    for (int off = 32; off > 0; off >>= 1) {
        s += __shfl_down(s, off); ss += __shfl_down(ss, off);
    }
    __shared__ float red[8];
    __shared__ float fin[2];
    const int wave = tid >> 6, lane = tid & 63;
    if (lane == 0) { red[wave * 2] = s; red[wave * 2 + 1] = ss; }
    __syncthreads();
    if (tid == 0) {
        float as = red[0] + red[2] + red[4] + red[6];
        float aq = red[1] + red[3] + red[5] + red[7];
        const float cnt = 32.f * NLO;
        float mu  = as / cnt;
        float var = aq / cnt - mu * mu;
        fin[0] = mu; fin[1] = rsqrtf(var + EPS_GN);
    }
    __syncthreads();
    if (tid < 32) {
        int c = g * 32 + tid;
        float sc = fin[1] * w[c];
        scale[b * 128 + c] = sc;
        shift[b * 128 + c] = bb[c] - fin[0] * sc;
    }
}

// ---------------------------------------------------------------------------
// 6) Elementwise gn+leakyrelu: y (B,NLO,128) bf16 -> yp bf16
// ---------------------------------------------------------------------------
__global__ void k_gnapply(const ushort* __restrict__ y, const float* __restrict__ sc,
                          const float* __restrict__ sh, ushort* __restrict__ yp) {
    long t = (long)blockIdx.x * 256 + threadIdx.x;
    const long total = (long)B_SZ * NLO * 16;
    if (t >= total) return;
    int  c8 = (int)(t & 15);
    long bn = t >> 4;
    int  b  = (int)(bn / NLO);
    short8 v = *(const short8*)&y[bn * 128 + c8 * 8];
    short8 o;
#pragma unroll
    for (int e = 0; e < 8; ++e) {
        int c = c8 * 8 + e;
        float f = bf2f((ushort)v[e]) * sc[b * 128 + c] + sh[b * 128 + c];
        f = fmaxf(f, SLOPE * f);
        o[e] = (short)f2bf(f);
    }
    *(short8*)&yp[bn * 128 + c8 * 8] = o;
}

// ---------------------------------------------------------------------------
// 7) Output: gn2 + leakyrelu + transpose (B,N,128) bf16 -> (B,128,N) f32
// ---------------------------------------------------------------------------
__global__ void k_output(const ushort* __restrict__ y2, const float* __restrict__ scale,
                         const float* __restrict__ shift, float* __restrict__ out) {
    __shared__ float t[32][129];
    const int b   = blockIdx.y;
    const int n0  = blockIdx.x * 32;
    const int tid = threadIdx.x;
    const float* scb = &scale[b * 128];
    const float* shb = &shift[b * 128];
    const int c8 = (tid & 15) * 8;
#pragma unroll
    for (int r = 0; r < 2; ++r) {
        int nn = (tid >> 4) + r * 16;
        int n  = n0 + nn;
        if (n < NLO) {
            short8 v = *(const short8*)&y2[((long)b * NLO + n) * 128 + c8];
#pragma unroll
            for (int e = 0; e < 8; ++e) {
                int c = c8 + e;
                float f = bf2f((ushort)v[e]) * scb[c] + shb[c];
                t[nn][c] = fmaxf(f, SLOPE * f);
            }
        } else {
#pragma unroll
            for (int e = 0; e < 8; ++e) t[nn][c8 + e] = 0.f;
        }
    }
    __syncthreads();
    const int n4 = (tid & 7) * 4;
    const bool full = (n0 + 32) <= NLO;
#pragma unroll
    for (int r = 0; r < 4; ++r) {
        int c = (tid >> 3) + r * 32;
        long o = ((long)b * 128 + c) * NLO + n0 + n4;
        if (full) {
            float2 v0 = make_float2(t[n4][c], t[n4 + 1][c]);
            float2 v1 = make_float2(t[n4 + 2][c], t[n4 + 3][c]);
            *(float2*)&out[o]     = v0;
            *(float2*)&out[o + 2] = v1;
        } else {
            for (int e = 0; e < 4; ++e)
                if (n0 + n4 + e < NLO) out[o + e] = t[n4 + e][c];
        }
    }
}

// ---------------------------------------------------------------------------
// Launch
// ---------------------------------------------------------------------------
extern "C" void kernel_launch(void* const* d_in, const int* in_sizes, int n_in,
                              void* d_out, int out_size, void* d_ws, size_t ws_size,
                              hipStream_t stream) {
    const float* x   = (const float*)d_in[0];
    const int*   pn  = (const int*)d_in[1];
    const int*   cn  = (const int*)d_in[2];
    const float* W1  = (const float*)d_in[3];
    const float* b1  = (const float*)d_in[4];
    const float* g1w = (const float*)d_in[5];
    const float* g1b = (const float*)d_in[6];
    const float* W2  = (const float*)d_in[7];
    const float* b2  = (const float*)d_in[8];
    const float* g2w = (const float*)d_in[9];
    const float* g2b = (const float*)d_in[10];
    float* out = (float*)d_out;
    char*  base = (char*)d_ws;

    ushort* xT  = (ushort*)(base + 0);           // 83,887,104 B
    ushort* y1  = (ushort*)(base + 0);           // reuse (xT dead after pool)
    ushort* y1p = (ushort*)(base + 44000000);
    ushort* h1  = (ushort*)(base + 88000000);
    ushort* y2  = (ushort*)(base + 110000000);
    ushort* wb1 = (ushort*)(base + 152000000);
    ushort* wb2 = (ushort*)(base + 152200000);
    float*  p1  = (float*)(base + 152500000);
    float*  p2  = (float*)(base + 152600000);
    float*  sc1 = (float*)(base + 152700000);
    float*  sh1 = sc1 + 512;
    float*  sc2 = (float*)(base + 152710000);
    float*  sh2 = sc2 + 512;

    const int NBLK = (NLO + 127) / 128;  // 321 conv blocks per batch

    k_transpose_x<<<dim3((NHI + 63) / 64, B_SZ), 256, 0, stream>>>(x, xT);
    k_prep_w<<<(448 * 128 + 255) / 256, 256, 0, stream>>>(W1, wb1, 448);
    k_prep_w<<<(896 * 128 + 255) / 256, 256, 0, stream>>>(W2, wb2, 896);
    k_pool<<<(int)(((long)B_SZ * NLO * 8 + 255) / 256), 256, 0, stream>>>(xT, pn, h1);
    k_conv_mfma<64><<<dim3(NBLK, B_SZ), 512, 0, stream>>>(h1, cn, wb1, b1, y1, p1);
    k_finalize<<<16, 256, 0, stream>>>(p1, NBLK, g1w, g1b, sc1, sh1);
    k_gnapply<<<(int)(((long)B_SZ * NLO * 16 + 255) / 256), 256, 0, stream>>>(y1, sc1, sh1, y1p);
    k_conv_mfma<128><<<dim3(NBLK, B_SZ), 512, 0, stream>>>(y1p, cn, wb2, b2, y2, p2);
    k_finalize<<<16, 256, 0, stream>>>(p2, NBLK, g2w, g2b, sc2, sh2);
    k_output<<<dim3((NLO + 31) / 32, B_SZ), 256, 0, stream>>>(y2, sc2, sh2, out);
}